// Round 8
// baseline (194.483 us; speedup 1.0000x reference)
//
#include <hip/hip_runtime.h>

#define NL 30
#define RPT 4                 // rows per thread
#define RPB (256 * RPT)       // 1024 rows per block

// Native ext-vector types (HIP float2/float4 classes rejected by
// __builtin_nontemporal_store).
typedef float v2f __attribute__((ext_vector_type(2)));
typedef float v4f __attribute__((ext_vector_type(4)));

// R8: amortize + hide param delivery.
// Ladder: R1 splat-movs / R6 ds_read lgkmcnt / R7 s_load waitcnt all = the
// SAME stall (per-layer param fetch latency >> 68cyc per-layer compute at
// 2 rows/thread); all cluster 63-72us vs 27us VALU floor.
// Fix: 4 rows/thread (136cyc compute/layer/wave, half the chip-wide s_load
// traffic) + explicit 1-layer param prefetch pipeline (SMEM covered by a
// full layer of compute). Shell unchanged from R7: scalar SGPR core,
// LDS-staged coalesced I/O, nt stores. 20KB slab -> 8 blocks/CU = 32 waves.
__global__ __launch_bounds__(256, 8) void drn_kernel(
    const float* __restrict__ x1, const float* __restrict__ x2,
    const float* __restrict__ W1, const float* __restrict__ b1,
    const float* __restrict__ W2,
    float* __restrict__ o1, float* __restrict__ o2)
{
    __shared__ __align__(16) float slab[RPB * 5];   // 20 KB

    const int t = threadIdx.x;
    const int base = blockIdx.x * RPB;

    // Stage x2 slab: lane-contiguous v4f (1024B/instr), 1280 v4f total.
    const v4f* g2 = (const v4f*)(x2 + (size_t)base * 5);
    v4f* s4 = (v4f*)slab;
    #pragma unroll
    for (int k = 0; k < 5; ++k)
        s4[t + 256 * k] = g2[t + 256 * k];

    float h1[RPT];
    #pragma unroll
    for (int r = 0; r < RPT; ++r) h1[r] = x1[base + 256 * r + t];

    __syncthreads();

    // Thread t owns rows t, t+256, t+512, t+768 (stride-5-dword reads:
    // 5 coprime 32 -> 2 lanes/bank = free).
    float h2[RPT][5];
    #pragma unroll
    for (int r = 0; r < RPT; ++r)
        #pragma unroll
        for (int j = 0; j < 5; ++j)
            h2[r][j] = slab[5 * (256 * r + t) + j];

    // Explicit 1-layer-deep param prefetch: load l+1 before computing l.
    float pw10 = W1[0], pw11 = W1[1], pw12 = W1[2], pw13 = W1[3], pw14 = W1[4];
    float pbb  = b1[0];
    float pw20 = W2[0], pw21 = W2[1], pw22 = W2[2], pw23 = W2[3], pw24 = W2[4];

    #pragma unroll
    for (int l = 0; l < NL; ++l) {
        const float w10 = pw10, w11 = pw11, w12 = pw12, w13 = pw13, w14 = pw14;
        const float bb  = pbb;
        const float w20 = pw20, w21 = pw21, w22 = pw22, w23 = pw23, w24 = pw24;
        if (l + 1 < NL) {
            const int n = (l + 1) * 5;
            pw10 = W1[n+0]; pw11 = W1[n+1]; pw12 = W1[n+2]; pw13 = W1[n+3]; pw14 = W1[n+4];
            pbb  = b1[l+1];
            pw20 = W2[n+0]; pw21 = W2[n+1]; pw22 = W2[n+2]; pw23 = W2[n+3]; pw24 = W2[n+4];
        }
        #pragma unroll
        for (int r = 0; r < RPT; ++r) {
            float s = h1[r] + bb;
            s = fmaf(fmaxf(h2[r][0], 0.f), w10, s);
            s = fmaf(fmaxf(h2[r][1], 0.f), w11, s);
            s = fmaf(fmaxf(h2[r][2], 0.f), w12, s);
            s = fmaf(fmaxf(h2[r][3], 0.f), w13, s);
            s = fmaf(fmaxf(h2[r][4], 0.f), w14, s);
            h1[r] = s;
            const float rh = fmaxf(s, 0.f);
            h2[r][0] = fmaf(rh, w20, h2[r][0]);
            h2[r][1] = fmaf(rh, w21, h2[r][1]);
            h2[r][2] = fmaf(rh, w22, h2[r][2]);
            h2[r][3] = fmaf(rh, w23, h2[r][3]);
            h2[r][4] = fmaf(rh, w24, h2[r][4]);
        }
    }

    #pragma unroll
    for (int r = 0; r < RPT; ++r)
        __builtin_nontemporal_store(h1[r], &o1[base + 256 * r + t]);

    // o2 via LDS transpose back to lane-contiguous v4f nt stores.
    __syncthreads();   // all slab reads complete before overwrite
    #pragma unroll
    for (int r = 0; r < RPT; ++r)
        #pragma unroll
        for (int j = 0; j < 5; ++j)
            slab[5 * (256 * r + t) + j] = h2[r][j];
    __syncthreads();
    v4f* go2 = (v4f*)(o2 + (size_t)base * 5);
    #pragma unroll
    for (int k = 0; k < 5; ++k)
        __builtin_nontemporal_store(s4[t + 256 * k], &go2[t + 256 * k]);
}

extern "C" void kernel_launch(void* const* d_in, const int* in_sizes, int n_in,
                              void* d_out, int out_size, void* d_ws, size_t ws_size,
                              hipStream_t stream) {
    const float* x1 = (const float*)d_in[0];
    const float* x2 = (const float*)d_in[1];
    const float* W1 = (const float*)d_in[2];
    const float* b1 = (const float*)d_in[3];
    const float* W2 = (const float*)d_in[4];
    int nrows = in_sizes[0];            // 4,194,304
    float* o1 = (float*)d_out;          // [nrows]
    float* o2 = (float*)d_out + nrows;  // [nrows*5]

    int block = 256;
    int grid = nrows / RPB;             // 4096 blocks, 4 rows/thread
    drn_kernel<<<grid, block, 0, stream>>>(x1, x2, W1, b1, W2, o1, o2);
}

// Round 10
// 192.424 us; speedup vs baseline: 1.0107x; 1.0107x over previous
//
#include <hip/hip_runtime.h>

#define NL 30
#define NBLK 2048            // 8 blocks/CU x 256 CU: one resident generation
#define NWAVES (NBLK * 4)    // 8192 waves, 128-row tiles, 4 tiles/wave

// Native ext-vector (HIP float2 class rejected by __builtin_nontemporal_store).
typedef float v2f __attribute__((ext_vector_type(2)));

// Zero-cost compiler memory fence. R9 post-mortem: LDS staged via v2f* writes
// but read via float* (and vice versa for the out-transpose). Clang TBAA
// treats those as non-aliasing -> ds_reads hoisted above ds_writes once the
// __syncthreads() barriers were removed -> compute read zero LDS (absmax
// ~= |ref|). Per-wave DS ops execute in order on CDNA, so a compiler-only
// fence restores correctness with zero emitted instructions (unlike
// __threadfence_block, which emits vmcnt(0) and would kill the prefetch).
#define LDS_FENCE() asm volatile("" ::: "memory")

// R10: wave-autonomous persistent tiles, ZERO barriers (R9 + fences).
// Each wave owns a private 640-float LDS section, loops over 4 tiles of 128
// rows; staging/transpose wave-internal; next tile's global loads issue
// before the ~2000cyc compute -> HBM latency covered; grid = one resident
// generation (no ramp, no tail).
__global__ __launch_bounds__(256, 8) void drn_kernel(
    const float* __restrict__ x1, const float* __restrict__ x2,
    const float* __restrict__ W1, const float* __restrict__ b1,
    const float* __restrict__ W2,
    float* __restrict__ o1, float* __restrict__ o2, int ntiles)
{
    __shared__ __align__(16) float slab[4 * 640];   // 2.5KB/wave, 10KB/block

    const int lane = threadIdx.x & 63;
    const int w    = threadIdx.x >> 6;
    float* sect  = &slab[w * 640];
    v2f*   sect2 = (v2f*)sect;

    const v2f* g2  = (const v2f*)x2;
    v2f*       go2 = (v2f*)o2;

    int tile = blockIdx.x * 4 + w;
    if (tile >= ntiles) return;

    // Prologue: tile0 loads (5x v2f = 512B/wave-instr, perfectly coalesced).
    v2f L[5];
    #pragma unroll
    for (int k = 0; k < 5; ++k) L[k] = g2[(size_t)tile * 320 + lane + 64 * k];
    float h1xn = x1[tile * 128 + lane];
    float h1yn = x1[tile * 128 + 64 + lane];

    while (true) {
        LDS_FENCE();   // WAR: staging writes must not hoist above prev out-reads
        // Stage current tile into this wave's section (contiguous b64 writes).
        #pragma unroll
        for (int k = 0; k < 5; ++k) sect2[lane + 64 * k] = L[k];
        const float h1x0 = h1xn, h1y0 = h1yn;

        LDS_FENCE();   // RAW: transposed float reads stay below v2f writes
        // Rows lane and lane+64 (stride-5 dwords: gcd(5,32)=1 -> conflict-free).
        float h2x[5], h2y[5];
        #pragma unroll
        for (int j = 0; j < 5; ++j) {
            h2x[j] = sect[5 * lane + j];
            h2y[j] = sect[320 + 5 * lane + j];
        }

        // Issue NEXT tile's global loads now; compute covers their latency.
        const int ntile = tile + NWAVES;
        const bool have_next = ntile < ntiles;
        if (have_next) {
            #pragma unroll
            for (int k = 0; k < 5; ++k) L[k] = g2[(size_t)ntile * 320 + lane + 64 * k];
            h1xn = x1[ntile * 128 + lane];
            h1yn = x1[ntile * 128 + 64 + lane];
        }

        // R7 scalar core: weights straight from SGPRs, no movs, no ds_reads.
        float h1x = h1x0, h1y = h1y0;
        #pragma unroll
        for (int l = 0; l < NL; ++l) {
            const float w10 = W1[l*5+0], w11 = W1[l*5+1], w12 = W1[l*5+2],
                        w13 = W1[l*5+3], w14 = W1[l*5+4];
            const float bb  = b1[l];
            const float w20 = W2[l*5+0], w21 = W2[l*5+1], w22 = W2[l*5+2],
                        w23 = W2[l*5+3], w24 = W2[l*5+4];
            {
                float s = h1x + bb;
                s = fmaf(fmaxf(h2x[0], 0.f), w10, s);
                s = fmaf(fmaxf(h2x[1], 0.f), w11, s);
                s = fmaf(fmaxf(h2x[2], 0.f), w12, s);
                s = fmaf(fmaxf(h2x[3], 0.f), w13, s);
                s = fmaf(fmaxf(h2x[4], 0.f), w14, s);
                h1x = s;
                const float rh = fmaxf(s, 0.f);
                h2x[0] = fmaf(rh, w20, h2x[0]);
                h2x[1] = fmaf(rh, w21, h2x[1]);
                h2x[2] = fmaf(rh, w22, h2x[2]);
                h2x[3] = fmaf(rh, w23, h2x[3]);
                h2x[4] = fmaf(rh, w24, h2x[4]);
            }
            {
                float s = h1y + bb;
                s = fmaf(fmaxf(h2y[0], 0.f), w10, s);
                s = fmaf(fmaxf(h2y[1], 0.f), w11, s);
                s = fmaf(fmaxf(h2y[2], 0.f), w12, s);
                s = fmaf(fmaxf(h2y[3], 0.f), w13, s);
                s = fmaf(fmaxf(h2y[4], 0.f), w14, s);
                h1y = s;
                const float rh = fmaxf(s, 0.f);
                h2y[0] = fmaf(rh, w20, h2y[0]);
                h2y[1] = fmaf(rh, w21, h2y[1]);
                h2y[2] = fmaf(rh, w22, h2y[2]);
                h2y[3] = fmaf(rh, w23, h2y[3]);
                h2y[4] = fmaf(rh, w24, h2y[4]);
            }
        }

        __builtin_nontemporal_store(h1x, &o1[tile * 128 + lane]);
        __builtin_nontemporal_store(h1y, &o1[tile * 128 + 64 + lane]);

        LDS_FENCE();   // WAR: out-transpose writes stay below transposed reads
        // o2: transpose back through the section (wave-internal, no barrier).
        #pragma unroll
        for (int j = 0; j < 5; ++j) {
            sect[5 * lane + j]       = h2x[j];
            sect[320 + 5 * lane + j] = h2y[j];
        }
        LDS_FENCE();   // RAW: v2f out-reads stay below float writes
        #pragma unroll
        for (int k = 0; k < 5; ++k)
            __builtin_nontemporal_store(sect2[lane + 64 * k],
                                        &go2[(size_t)tile * 320 + lane + 64 * k]);

        if (!have_next) break;
        tile = ntile;
    }
}

extern "C" void kernel_launch(void* const* d_in, const int* in_sizes, int n_in,
                              void* d_out, int out_size, void* d_ws, size_t ws_size,
                              hipStream_t stream) {
    const float* x1 = (const float*)d_in[0];
    const float* x2 = (const float*)d_in[1];
    const float* W1 = (const float*)d_in[2];
    const float* b1 = (const float*)d_in[3];
    const float* W2 = (const float*)d_in[4];
    int nrows = in_sizes[0];            // 4,194,304
    float* o1 = (float*)d_out;          // [nrows]
    float* o2 = (float*)d_out + nrows;  // [nrows*5]

    int ntiles = nrows / 128;           // 32768 tiles, 4 per wave
    drn_kernel<<<NBLK, 256, 0, stream>>>(x1, x2, W1, b1, W2, o1, o2, ntiles);
}

// Round 11
// 189.057 us; speedup vs baseline: 1.0287x; 1.0178x over previous
//
#include <hip/hip_runtime.h>

#define NL 30
#define RPB 512              // rows per block (2 rows/thread, 256 threads)

// v2f only for staging (native ext-vector works with nontemporal builtin).
typedef float v2f __attribute__((ext_vector_type(2)));

// FINAL (session best = R7, 63.5us/dispatch, restored after R8/R10 regressions).
// Why this shape won:
//  - scalar core, weights as direct SGPR operands (v_fma_f32 v,v,s,v): zero
//    param-delivery VALU cost (R1's splat-movs and R0/R6's ds_reads were the
//    delivery tax; both cluster 67-78us).
//  - v_pk_*_f32 gains nothing: fp32 peak = unpacked rate; pk = 4 issue cyc
//    (confirmed R3-vs-R7 busy equality). 17 ops/row/layer is algebraically
//    irreducible past the relu chain; bf16/f16 numerically closed (|out|~1e6,
//    abs threshold 5.5).
//  - x2/o2 staged through LDS: global side lane-contiguous v2f (zero
//    transaction amplification), LDS side stride-5 dword (gcd(5,32)=1 ->
//    2 lanes/bank = free).
//  - VALU floor ~42-45us at sustained clock (~1.6GHz under dense FMA, m07);
//    busy here ~48us; remaining ~25% idle resisted 4-row (R8), explicit
//    param prefetch (R8), and barrier-free wave-autonomous persistence (R10).
__global__ __launch_bounds__(256) void drn_kernel(
    const float* __restrict__ x1, const float* __restrict__ x2,
    const float* __restrict__ W1, const float* __restrict__ b1,
    const float* __restrict__ W2,
    float* __restrict__ o1, float* __restrict__ o2)
{
    __shared__ __align__(16) float slab[RPB * 5];   // 10 KB

    const int t = threadIdx.x;
    const int base = blockIdx.x * RPB;

    // Stage x2 slab: lane-contiguous v2f (512B/instr, zero amplification).
    const v2f* g2 = (const v2f*)(x2 + (size_t)base * 5);
    v2f* s2 = (v2f*)slab;
    #pragma unroll
    for (int k = 0; k < 5; ++k)
        s2[t + 256 * k] = g2[t + 256 * k];

    float h1x = x1[base + t];
    float h1y = x1[base + 256 + t];

    __syncthreads();

    // Rows t and t+256, slab-local (stride-5 dword reads: conflict-free).
    float h2x[5], h2y[5];
    #pragma unroll
    for (int j = 0; j < 5; ++j) {
        h2x[j] = slab[5 * t + j];
        h2y[j] = slab[5 * t + 1280 + j];
    }

    #pragma unroll
    for (int l = 0; l < NL; ++l) {
        // Uniform scalar loads -> SGPRs (compiler prefetches across unroll;
        // 1.4KB of params is scalar-L1-resident after the first wave).
        const float w10 = W1[l * 5 + 0], w11 = W1[l * 5 + 1], w12 = W1[l * 5 + 2],
                    w13 = W1[l * 5 + 3], w14 = W1[l * 5 + 4];
        const float bb  = b1[l];
        const float w20 = W2[l * 5 + 0], w21 = W2[l * 5 + 1], w22 = W2[l * 5 + 2],
                    w23 = W2[l * 5 + 3], w24 = W2[l * 5 + 4];

        // row x
        {
            float s = h1x + bb;
            s = fmaf(fmaxf(h2x[0], 0.f), w10, s);
            s = fmaf(fmaxf(h2x[1], 0.f), w11, s);
            s = fmaf(fmaxf(h2x[2], 0.f), w12, s);
            s = fmaf(fmaxf(h2x[3], 0.f), w13, s);
            s = fmaf(fmaxf(h2x[4], 0.f), w14, s);
            h1x = s;
            const float rh = fmaxf(s, 0.f);
            h2x[0] = fmaf(rh, w20, h2x[0]);
            h2x[1] = fmaf(rh, w21, h2x[1]);
            h2x[2] = fmaf(rh, w22, h2x[2]);
            h2x[3] = fmaf(rh, w23, h2x[3]);
            h2x[4] = fmaf(rh, w24, h2x[4]);
        }
        // row y
        {
            float s = h1y + bb;
            s = fmaf(fmaxf(h2y[0], 0.f), w10, s);
            s = fmaf(fmaxf(h2y[1], 0.f), w11, s);
            s = fmaf(fmaxf(h2y[2], 0.f), w12, s);
            s = fmaf(fmaxf(h2y[3], 0.f), w13, s);
            s = fmaf(fmaxf(h2y[4], 0.f), w14, s);
            h1y = s;
            const float rh = fmaxf(s, 0.f);
            h2y[0] = fmaf(rh, w20, h2y[0]);
            h2y[1] = fmaf(rh, w21, h2y[1]);
            h2y[2] = fmaf(rh, w22, h2y[2]);
            h2y[3] = fmaf(rh, w23, h2y[3]);
            h2y[4] = fmaf(rh, w24, h2y[4]);
        }
    }

    __builtin_nontemporal_store(h1x, &o1[base + t]);
    __builtin_nontemporal_store(h1y, &o1[base + 256 + t]);

    // o2 via LDS transpose back to lane-contiguous v2f nt stores.
    __syncthreads();   // all slab reads complete before overwrite
    #pragma unroll
    for (int j = 0; j < 5; ++j) {
        slab[5 * t + j]        = h2x[j];
        slab[5 * t + 1280 + j] = h2y[j];
    }
    __syncthreads();
    v2f* go2 = (v2f*)(o2 + (size_t)base * 5);
    #pragma unroll
    for (int k = 0; k < 5; ++k)
        __builtin_nontemporal_store(s2[t + 256 * k], &go2[t + 256 * k]);
}

extern "C" void kernel_launch(void* const* d_in, const int* in_sizes, int n_in,
                              void* d_out, int out_size, void* d_ws, size_t ws_size,
                              hipStream_t stream) {
    const float* x1 = (const float*)d_in[0];
    const float* x2 = (const float*)d_in[1];
    const float* W1 = (const float*)d_in[2];
    const float* b1 = (const float*)d_in[3];
    const float* W2 = (const float*)d_in[4];
    int nrows = in_sizes[0];            // 4,194,304
    float* o1 = (float*)d_out;          // [nrows]
    float* o2 = (float*)d_out + nrows;  // [nrows*5]

    int block = 256;
    int grid = nrows / RPB;             // 8192 blocks, 2 rows/thread
    drn_kernel<<<grid, block, 0, stream>>>(x1, x2, W1, b1, W2, o1, o2);
}